// Round 7
// baseline (247.801 us; speedup 1.0000x reference)
//
#include <hip/hip_runtime.h>
#include <hip/hip_bf16.h>
#include <stdint.h>

#define H_DIM 1024
#define QMAX 127.0f
#define CLIP 2.5f

typedef __attribute__((ext_vector_type(4))) float f32x4;
typedef __attribute__((ext_vector_type(8))) short bf16x8;
typedef __attribute__((ext_vector_type(8))) unsigned short u16x8;
typedef __attribute__((address_space(3))) void lds_void;
typedef const __attribute__((address_space(1))) void gmem_void;

// ---------------------------------------------------------------------------
// absmax of clip(x,-CLIP,CLIP) (n%4==0), atomicMax into *out (pre-zeroed).
// ---------------------------------------------------------------------------
__global__ __launch_bounds__(256) void absmax_clip_kernel(
    const float* __restrict__ x, long n, float* __restrict__ out) {
  float m = 0.f;
  const long stride = (long)gridDim.x * blockDim.x * 4;
  for (long i = ((long)blockIdx.x * blockDim.x + threadIdx.x) * 4; i < n; i += stride) {
    const float4 v = *reinterpret_cast<const float4*>(x + i);
    m = fmaxf(m, fmaxf(fmaxf(fabsf(v.x), fabsf(v.y)), fmaxf(fabsf(v.z), fabsf(v.w))));
  }
  m = fminf(m, CLIP);
#pragma unroll
  for (int off = 32; off > 0; off >>= 1) m = fmaxf(m, __shfl_down(m, off));
  __shared__ float red[4];
  const int lane = threadIdx.x & 63, w = threadIdx.x >> 6;
  if (lane == 0) red[w] = m;
  __syncthreads();
  if (threadIdx.x == 0) {
    const float mm = fmaxf(fmaxf(red[0], red[1]), fmaxf(red[2], red[3]));
    atomicMax(reinterpret_cast<unsigned int*>(out), __float_as_uint(mm));
  }
}

__device__ __forceinline__ unsigned short quant_bf16(float x, float s) {
  // round(clip(x)*s) is an integer in [-127,127] -> exact in bf16.
  const float q = rintf(fminf(fmaxf(x, -CLIP), CLIP) * s);
  return (unsigned short)(__float_as_uint(q) >> 16);
}

__device__ __forceinline__ unsigned short f2bf_rne(float f) {
  const unsigned u = __float_as_uint(f);
  return (unsigned short)((u + 0x7FFFu + ((u >> 16) & 1u)) >> 16);
}

__device__ __forceinline__ float bf2f(unsigned short u) {
  return __uint_as_float((unsigned)u << 16);
}

// ---------------------------------------------------------------------------
// Quantize fp32 -> bf16 integer values (grid-stride, n%4==0).
// ---------------------------------------------------------------------------
__global__ __launch_bounds__(256) void quant_kernel(
    const float* __restrict__ x, unsigned short* __restrict__ q,
    const float* __restrict__ amax_p, long n) {
  const float s = QMAX / fmaxf(amax_p[0], 1e-8f);
  const long stride = (long)gridDim.x * blockDim.x * 4;
  for (long i = ((long)blockIdx.x * blockDim.x + threadIdx.x) * 4; i < n; i += stride) {
    const float4 v = *reinterpret_cast<const float4*>(x + i);
    ushort4 o;
    o.x = quant_bf16(v.x, s);
    o.y = quant_bf16(v.y, s);
    o.z = quant_bf16(v.z, s);
    o.w = quant_bf16(v.w, s);
    *reinterpret_cast<ushort4*>(q + i) = o;
  }
}

// ===========================================================================
// gemm_s: pre-quantized GEMM + bias + resid -> ybf (bf16).
// 128x128 tile, BK=32, 256 thr (4 waves 2x2), 16x16x32 MFMA, 4x4 frags/wave.
// K-loop: T4 counted-vmcnt double buffer --
//   stage(nxt) ; vmcnt(4) ; s_barrier ; ds_read(cur)+MFMA ; s_barrier
// tile(it+1)'s loads stay in flight across the whole MFMA phase; never
// drained to 0 until the last iteration.  Swizzled staging/reads (0-conflict,
// r3/r5/r6-verified).  Epilogue: bf16 LDS bounce -> coalesced readout that
// adds resid (float4, same addresses as stores) -> ybf.
// ===========================================================================
#define BMs 128
#define BNs 128
#define BKs 32
#define NITs (H_DIM / BKs)

__global__ __launch_bounds__(256) void gemm_s_kernel(
    const unsigned short* __restrict__ Aq,   // [M][1024] bf16 ints
    const unsigned short* __restrict__ Wq,   // [1024][1024] bf16 ints
    const float* __restrict__ bias,
    const float* __restrict__ resid,
    const float* __restrict__ scales,
    unsigned short* __restrict__ ybf, int M) {
  // SM: K-loop uses [0..16383] (As 2x4096, Bs 2x4096); epilogue bounce
  // reuses [0..17407] as 128 rows x 136 ushorts.
  __shared__ __attribute__((aligned(16))) unsigned short SM[17408];
  unsigned short* As = SM;          // [2][128*32]
  unsigned short* Bs = SM + 8192;   // [2][128*32]

  const int nwg = (M / BMs) * 8;
  const int orig = blockIdx.x;
  const int cpx = nwg >> 3;
  const int wg = ((nwg & 7) == 0) ? ((orig & 7) * cpx + (orig >> 3)) : orig;
  const int bn = wg & 7, bm = wg >> 3;      // bn fast -> A panel L2 reuse
  const int m0 = bm * BMs, n0 = bn * BNs;

  const int t = threadIdx.x;
  const int lane = t & 63, wid = t >> 6;
  const int wr = wid >> 1, wc = wid & 1;
  const int lrow = lane & 15, lgrp = lane >> 4;

  const float amax_h = fmaxf(scales[0], 1e-8f);
  const float amax_w = fmaxf(scales[1], 1e-8f);
  const float inv_s = (amax_h * amax_w) / (QMAX * QMAX);

  // staging: chunks c0=t, c1=t+256 -> row c>>2, 16B grp c&3; global source
  // col-group inverse-swizzled so swizzled reads see linear data.
  const int c0 = t, c1 = t + 256;
  const int r0 = c0 >> 2, r1 = c1 >> 2;
  const unsigned g0 = (unsigned)r0 * H_DIM + (unsigned)((((c0 & 3) ^ ((r0 >> 1) & 3))) * 8);
  const unsigned g1 = (unsigned)r1 * H_DIM + (unsigned)((((c1 & 3) ^ ((r1 >> 1) & 3))) * 8);
  const unsigned short* Ag = Aq + (size_t)m0 * H_DIM;
  const unsigned short* Bg = Wq + (size_t)n0 * H_DIM;

#define STAGE_T(BUF, KQ)                                                       \
  { __builtin_amdgcn_global_load_lds((gmem_void*)(Ag + g0 + (KQ)),             \
        (lds_void*)(As + (BUF)*4096 + c0 * 8), 16, 0, 0);                      \
    __builtin_amdgcn_global_load_lds((gmem_void*)(Ag + g1 + (KQ)),             \
        (lds_void*)(As + (BUF)*4096 + c1 * 8), 16, 0, 0);                      \
    __builtin_amdgcn_global_load_lds((gmem_void*)(Bg + g0 + (KQ)),             \
        (lds_void*)(Bs + (BUF)*4096 + c0 * 8), 16, 0, 0);                      \
    __builtin_amdgcn_global_load_lds((gmem_void*)(Bg + g1 + (KQ)),             \
        (lds_void*)(Bs + (BUF)*4096 + c1 * 8), 16, 0, 0); }

  // swizzled per-thread LDS read offsets (ushorts)
  int offA[4], offB[4];
#pragma unroll
  for (int i = 0; i < 4; ++i) {
    const int r = wr * 64 + i * 16 + lrow;
    offA[i] = r * 32 + ((lgrp ^ ((r >> 1) & 3)) * 8);
  }
#pragma unroll
  for (int j = 0; j < 4; ++j) {
    const int r = wc * 64 + j * 16 + lrow;
    offB[j] = r * 32 + ((lgrp ^ ((r >> 1) & 3)) * 8);
  }

  f32x4 acc[4][4];
#pragma unroll
  for (int i = 0; i < 4; i++)
#pragma unroll
    for (int j = 0; j < 4; j++)
#pragma unroll
      for (int r = 0; r < 4; r++) acc[i][j][r] = 0.f;

  // prologue: tile 0 -> buffer 0 (4 loads in flight)
  STAGE_T(0, 0)

  for (int it = 0; it < NITs; ++it) {
    const int cur = it & 1, nxt = cur ^ 1;
    if (it + 1 < NITs) {
      STAGE_T(nxt, (unsigned)((it + 1) * BKs))
      asm volatile("s_waitcnt vmcnt(4)" ::: "memory");  // tile it landed; it+1 in flight
    } else {
      asm volatile("s_waitcnt vmcnt(0)" ::: "memory");  // drain last tile
    }
    __builtin_amdgcn_s_barrier();                       // all waves: cur ready
    __builtin_amdgcn_sched_barrier(0);

    bf16x8 af[4], bfr[4];
#pragma unroll
    for (int i = 0; i < 4; ++i)
      af[i] = *reinterpret_cast<const bf16x8*>(As + cur * 4096 + offA[i]);
#pragma unroll
    for (int j = 0; j < 4; ++j)
      bfr[j] = *reinterpret_cast<const bf16x8*>(Bs + cur * 4096 + offB[j]);
    __builtin_amdgcn_s_setprio(1);
#pragma unroll
    for (int i = 0; i < 4; ++i)
#pragma unroll
      for (int j = 0; j < 4; ++j)
        acc[i][j] = __builtin_amdgcn_mfma_f32_16x16x32_bf16(af[i], bfr[j], acc[i][j], 0, 0, 0);
    __builtin_amdgcn_s_setprio(0);
    __builtin_amdgcn_s_barrier();                       // all waves done reading cur
  }
#undef STAGE_T

  // epilogue: bounce bf16(acc*inv_s + bias) into SM
#pragma unroll
  for (int j = 0; j < 4; ++j) {
    const int cl = wc * 64 + j * 16 + lrow;
    const float bv = bias[n0 + cl];
#pragma unroll
    for (int i = 0; i < 4; ++i) {
      const int rl0 = wr * 64 + i * 16 + lgrp * 4;
#pragma unroll
      for (int r = 0; r < 4; ++r)
        SM[(rl0 + r) * 136 + cl] = f2bf_rne(acc[i][j][r] * inv_s + bv);
    }
  }
  __syncthreads();
  // coalesced readout: add resid (float4, same addresses) -> ybf
  {
    const int e_row = t >> 1, e_half = t & 1;
    const size_t gb = (size_t)(m0 + e_row) * H_DIM + n0 + e_half * 64;
    const unsigned short* src = SM + e_row * 136 + e_half * 64;
    unsigned short* dst = ybf + gb;
    const float* rsd = resid + gb;
#pragma unroll
    for (int c = 0; c < 8; ++c) {
      const u16x8 g = *reinterpret_cast<const u16x8*>(src + c * 8);
      const float4 rA = *reinterpret_cast<const float4*>(rsd + c * 8);
      const float4 rB = *reinterpret_cast<const float4*>(rsd + c * 8 + 4);
      u16x8 o;
      o[0] = f2bf_rne(bf2f(g[0]) + rA.x);
      o[1] = f2bf_rne(bf2f(g[1]) + rA.y);
      o[2] = f2bf_rne(bf2f(g[2]) + rA.z);
      o[3] = f2bf_rne(bf2f(g[3]) + rA.w);
      o[4] = f2bf_rne(bf2f(g[4]) + rB.x);
      o[5] = f2bf_rne(bf2f(g[5]) + rB.y);
      o[6] = f2bf_rne(bf2f(g[6]) + rB.z);
      o[7] = f2bf_rne(bf2f(g[7]) + rB.w);
      *reinterpret_cast<u16x8*>(dst + c * 8) = o;
    }
  }
}

// ---------------------------------------------------------------------------
// ln_bf16: LayerNorm(bf16 y) -> fp32 out. 2 rows/block (256 thr), 8 cols/thr.
// ---------------------------------------------------------------------------
__global__ __launch_bounds__(256) void ln_bf16_kernel(
    const unsigned short* __restrict__ ybf, const float* __restrict__ gamma,
    const float* __restrict__ beta, float* __restrict__ out) {
  const int rl = threadIdx.x >> 7;            // row within block (0/1)
  const int c0 = (threadIdx.x & 127) * 8;     // 8 cols per thread
  const size_t base = ((size_t)blockIdx.x * 2 + rl) * H_DIM + c0;

  const u16x8 g = *reinterpret_cast<const u16x8*>(ybf + base);
  float v[8];
#pragma unroll
  for (int k = 0; k < 8; ++k) v[k] = bf2f(g[k]);

  float s = 0.f, ss = 0.f;
#pragma unroll
  for (int k = 0; k < 8; ++k) { s += v[k]; ss += v[k] * v[k]; }
#pragma unroll
  for (int off = 32; off > 0; off >>= 1) {
    s += __shfl_down(s, off);
    ss += __shfl_down(ss, off);
  }
  __shared__ float red[4][2];
  const int lane = threadIdx.x & 63, w = threadIdx.x >> 6;  // waves 0,1->row0; 2,3->row1
  if (lane == 0) { red[w][0] = s; red[w][1] = ss; }
  __syncthreads();
  const int wp = rl * 2;
  const float stot = red[wp][0] + red[wp + 1][0];
  const float sstot = red[wp][1] + red[wp + 1][1];
  const float mu = stot * (1.0f / H_DIM);
  const float var = fmaxf(sstot * (1.0f / H_DIM) - mu * mu, 0.f);
  const float rs = rsqrtf(var + 1e-12f);

  const float4 gA = *reinterpret_cast<const float4*>(gamma + c0);
  const float4 gB = *reinterpret_cast<const float4*>(gamma + c0 + 4);
  const float4 bA = *reinterpret_cast<const float4*>(beta + c0);
  const float4 bB = *reinterpret_cast<const float4*>(beta + c0 + 4);
  float4 oA, oB;
  oA.x = (v[0] - mu) * rs * gA.x + bA.x;
  oA.y = (v[1] - mu) * rs * gA.y + bA.y;
  oA.z = (v[2] - mu) * rs * gA.z + bA.z;
  oA.w = (v[3] - mu) * rs * gA.w + bA.w;
  oB.x = (v[4] - mu) * rs * gB.x + bB.x;
  oB.y = (v[5] - mu) * rs * gB.y + bB.y;
  oB.z = (v[6] - mu) * rs * gB.z + bB.z;
  oB.w = (v[7] - mu) * rs * gB.w + bB.w;
  *reinterpret_cast<float4*>(out + base) = oA;
  *reinterpret_cast<float4*>(out + base + 4) = oB;
}

// ===========================================================================
// Tier-2 fallback (round-5 validated): fused-quant GEMM + resid -> ybf.
// ===========================================================================
#define BMv 128
#define BNv 128
#define BKv 32

__global__ __launch_bounds__(256) void gemm_fa_kernel(
    const float* __restrict__ hidden, const unsigned short* __restrict__ Wq,
    const float* __restrict__ bias, const float* __restrict__ resid,
    const float* __restrict__ scales, unsigned short* __restrict__ ybf, int M) {
  __shared__ __attribute__((aligned(16))) unsigned short SM[17408];
  unsigned short* As = SM;
  unsigned short* Bs = SM + 8192;
  const int nwg = (M / BMv) * 8;
  const int orig = blockIdx.x;
  const int cpx = nwg >> 3;
  const int wg = ((nwg & 7) == 0) ? ((orig & 7) * cpx + (orig >> 3)) : orig;
  const int bn = wg & 7, bm = wg >> 3;
  const int m0 = bm * BMv, n0 = bn * BNv;
  const int t = threadIdx.x;
  const int lane = t & 63, wid = t >> 6;
  const int wr = wid >> 1, wc = wid & 1;
  const int lrow = lane & 15, lgrp = lane >> 4;
  const float amax_h = fmaxf(scales[0], 1e-8f);
  const float amax_w = fmaxf(scales[1], 1e-8f);
  const float sh = QMAX / amax_h;
  const float inv_s = (amax_h * amax_w) / (QMAX * QMAX);
  const int a_row = t >> 1, a_half = t & 1;
  const float* Ag = hidden + (size_t)(m0 + a_row) * H_DIM + a_half * 16;
  const int a_swz = (a_row >> 1) & 3;
  const int aw0 = a_row * 32 + (((a_half * 2 + 0) ^ a_swz) * 8);
  const int aw1 = a_row * 32 + (((a_half * 2 + 1) ^ a_swz) * 8);
  const int bc0 = t, bc1 = t + 256;
  const int br0 = bc0 >> 2, br1 = bc1 >> 2;
  const unsigned bg0 = (unsigned)br0 * H_DIM + (unsigned)((((bc0 & 3) ^ ((br0 >> 1) & 3))) * 8);
  const unsigned bg1 = (unsigned)br1 * H_DIM + (unsigned)((((bc1 & 3) ^ ((br1 >> 1) & 3))) * 8);
  const unsigned short* Bg = Wq + (size_t)n0 * H_DIM;
  int offA[4], offB[4];
#pragma unroll
  for (int i = 0; i < 4; ++i) {
    const int r = wr * 64 + i * 16 + lrow;
    offA[i] = r * 32 + ((lgrp ^ ((r >> 1) & 3)) * 8);
  }
#pragma unroll
  for (int j = 0; j < 4; ++j) {
    const int r = wc * 64 + j * 16 + lrow;
    offB[j] = r * 32 + ((lgrp ^ ((r >> 1) & 3)) * 8);
  }
  f32x4 acc[4][4];
#pragma unroll
  for (int i = 0; i < 4; i++)
#pragma unroll
    for (int j = 0; j < 4; j++)
#pragma unroll
      for (int r = 0; r < 4; r++) acc[i][j][r] = 0.f;
#define QUANT_PACK(dst0, dst1, v0, v1, v2, v3)                                 \
  {                                                                            \
    u16x8 p0, p1;                                                              \
    p0[0] = quant_bf16((v0).x, sh); p0[1] = quant_bf16((v0).y, sh);            \
    p0[2] = quant_bf16((v0).z, sh); p0[3] = quant_bf16((v0).w, sh);            \
    p0[4] = quant_bf16((v1).x, sh); p0[5] = quant_bf16((v1).y, sh);            \
    p0[6] = quant_bf16((v1).z, sh); p0[7] = quant_bf16((v1).w, sh);            \
    p1[0] = quant_bf16((v2).x, sh); p1[1] = quant_bf16((v2).y, sh);            \
    p1[2] = quant_bf16((v2).z, sh); p1[3] = quant_bf16((v2).w, sh);            \
    p1[4] = quant_bf16((v3).x, sh); p1[5] = quant_bf16((v3).y, sh);            \
    p1[6] = quant_bf16((v3).z, sh); p1[7] = quant_bf16((v3).w, sh);            \
    *reinterpret_cast<u16x8*>(dst0) = p0;                                      \
    *reinterpret_cast<u16x8*>(dst1) = p1;                                      \
  }
  {
    const float4 v0 = *reinterpret_cast<const float4*>(Ag + 0);
    const float4 v1 = *reinterpret_cast<const float4*>(Ag + 4);
    const float4 v2 = *reinterpret_cast<const float4*>(Ag + 8);
    const float4 v3 = *reinterpret_cast<const float4*>(Ag + 12);
    __builtin_amdgcn_global_load_lds((gmem_void*)(Bg + bg0), (lds_void*)(Bs + bc0 * 8), 16, 0, 0);
    __builtin_amdgcn_global_load_lds((gmem_void*)(Bg + bg1), (lds_void*)(Bs + bc1 * 8), 16, 0, 0);
    QUANT_PACK(As + aw0, As + aw1, v0, v1, v2, v3)
    __syncthreads();
  }
  for (int it = 0; it < H_DIM / BKv; ++it) {
    const int cur = it & 1, nxt = cur ^ 1;
    const bool more = (it + 1) < (H_DIM / BKv);
    float4 v0, v1, v2, v3;
    if (more) {
      const float* Agn = Ag + (it + 1) * BKv;
      v0 = *reinterpret_cast<const float4*>(Agn + 0);
      v1 = *reinterpret_cast<const float4*>(Agn + 4);
      v2 = *reinterpret_cast<const float4*>(Agn + 8);
      v3 = *reinterpret_cast<const float4*>(Agn + 12);
      const unsigned kq = (unsigned)((it + 1) * BKv);
      __builtin_amdgcn_global_load_lds((gmem_void*)(Bg + bg0 + kq),
                                       (lds_void*)(Bs + nxt * 4096 + bc0 * 8), 16, 0, 0);
      __builtin_amdgcn_global_load_lds((gmem_void*)(Bg + bg1 + kq),
                                       (lds_void*)(Bs + nxt * 4096 + bc1 * 8), 16, 0, 0);
    }
    bf16x8 af[4], bfr[4];
#pragma unroll
    for (int i = 0; i < 4; ++i)
      af[i] = *reinterpret_cast<const bf16x8*>(As + cur * 4096 + offA[i]);
#pragma unroll
    for (int j = 0; j < 4; ++j)
      bfr[j] = *reinterpret_cast<const bf16x8*>(Bs + cur * 4096 + offB[j]);
    __builtin_amdgcn_s_setprio(1);
#pragma unroll
    for (int i = 0; i < 4; ++i)
#pragma unroll
      for (int j = 0; j < 4; ++j)
        acc[i][j] = __builtin_amdgcn_mfma_f32_16x16x32_bf16(af[i], bfr[j], acc[i][j], 0, 0, 0);
    __builtin_amdgcn_s_setprio(0);
    if (more) {
      QUANT_PACK(As + nxt * 4096 + aw0, As + nxt * 4096 + aw1, v0, v1, v2, v3)
    }
    __syncthreads();
  }
#pragma unroll
  for (int j = 0; j < 4; ++j) {
    const int cl = wc * 64 + j * 16 + lrow;
    const float bv = bias[n0 + cl];
#pragma unroll
    for (int i = 0; i < 4; ++i) {
      const int rl0 = wr * 64 + i * 16 + lgrp * 4;
#pragma unroll
      for (int r = 0; r < 4; ++r) {
        const float y = acc[i][j][r] * inv_s + bv +
                        resid[(size_t)(m0 + rl0 + r) * H_DIM + n0 + cl];
        SM[(rl0 + r) * 136 + cl] = f2bf_rne(y);
      }
    }
  }
  __syncthreads();
  {
    const int e_row = t >> 1, e_half = t & 1;
    unsigned short* dst = ybf + (size_t)(m0 + e_row) * H_DIM + n0 + e_half * 64;
    const unsigned short* src = SM + e_row * 136 + e_half * 64;
#pragma unroll
    for (int c = 0; c < 8; ++c)
      *reinterpret_cast<u16x8*>(dst + c * 8) =
          *reinterpret_cast<const u16x8*>(src + c * 8);
  }
#undef QUANT_PACK
}

// ===========================================================================
// Tier-3 fallback (round-1 validated).
// ===========================================================================
#define BM 128
#define BN 128
#define BK 32

__global__ __launch_bounds__(256, 2) void gemm_fused_kernel(
    const float* __restrict__ A, const unsigned short* __restrict__ Wq,
    const float* __restrict__ bias, const float* __restrict__ resid,
    const float* __restrict__ scales, float* __restrict__ out, int M) {
  __shared__ unsigned short Asf[BM][40];
  __shared__ unsigned short Bsf[BN][40];
  const int nbm = M / BM;
  const int bm = blockIdx.x % nbm, bn = blockIdx.x / nbm;
  const int m0 = bm * BM, n0 = bn * BN;
  const int t = threadIdx.x;
  const int lane = t & 63, wid = t >> 6;
  const int wr = wid >> 1, wc = wid & 1;
  const int lrow = lane & 15, lgrp = lane >> 4;
  const float amax_h = fmaxf(scales[0], 1e-8f);
  const float amax_w = fmaxf(scales[1], 1e-8f);
  const float sh = QMAX / amax_h;
  const float inv_s = (amax_h * amax_w) / (QMAX * QMAX);
  f32x4 acc[4][4];
#pragma unroll
  for (int i = 0; i < 4; i++)
#pragma unroll
    for (int j = 0; j < 4; j++)
#pragma unroll
      for (int r = 0; r < 4; r++) acc[i][j][r] = 0.f;
  for (int k0 = 0; k0 < H_DIM; k0 += BK) {
#pragma unroll
    for (int j = 0; j < 4; ++j) {
      const int f = j * 256 + t;
      const int r = f >> 3, c4 = f & 7;
      const float4 v = *reinterpret_cast<const float4*>(A + (size_t)(m0 + r) * H_DIM + k0 + c4 * 4);
      ushort4 q;
      q.x = quant_bf16(v.x, sh); q.y = quant_bf16(v.y, sh);
      q.z = quant_bf16(v.z, sh); q.w = quant_bf16(v.w, sh);
      *reinterpret_cast<ushort4*>(&Asf[r][c4 * 4]) = q;
    }
#pragma unroll
    for (int j = 0; j < 2; ++j) {
      const int f = j * 256 + t;
      const int r = f >> 2, cb = f & 3;
      const uint4 v = *reinterpret_cast<const uint4*>(Wq + (size_t)(n0 + r) * H_DIM + k0 + cb * 8);
      *reinterpret_cast<uint4*>(&Bsf[r][cb * 8]) = v;
    }
    __syncthreads();
    bf16x8 af[4], bfr[4];
#pragma unroll
    for (int i = 0; i < 4; i++)
      af[i] = *reinterpret_cast<const bf16x8*>(&Asf[wr * 64 + i * 16 + lrow][lgrp * 8]);
#pragma unroll
    for (int j = 0; j < 4; j++)
      bfr[j] = *reinterpret_cast<const bf16x8*>(&Bsf[wc * 64 + j * 16 + lrow][lgrp * 8]);
#pragma unroll
    for (int i = 0; i < 4; i++)
#pragma unroll
      for (int j = 0; j < 4; j++)
        acc[i][j] = __builtin_amdgcn_mfma_f32_16x16x32_bf16(af[i], bfr[j], acc[i][j], 0, 0, 0);
    __syncthreads();
  }
#pragma unroll
  for (int j = 0; j < 4; j++) {
    const int col = n0 + wc * 64 + j * 16 + lrow;
    const float bv = bias[col];
#pragma unroll
    for (int i = 0; i < 4; i++) {
      const int row0 = m0 + wr * 64 + i * 16 + lgrp * 4;
#pragma unroll
      for (int r = 0; r < 4; r++) {
        const size_t off = (size_t)(row0 + r) * H_DIM + col;
        out[off] = acc[i][j][r] * inv_s + bv + resid[off];
      }
    }
  }
}

__global__ __launch_bounds__(256) void ln_kernel(
    float* __restrict__ y, const float* __restrict__ gamma,
    const float* __restrict__ beta) {
  const size_t base = (size_t)blockIdx.x * H_DIM + threadIdx.x * 4;
  const float4 v = *reinterpret_cast<const float4*>(y + base);
  float s = v.x + v.y + v.z + v.w;
  float ss = v.x * v.x + v.y * v.y + v.z * v.z + v.w * v.w;
#pragma unroll
  for (int off = 32; off > 0; off >>= 1) {
    s += __shfl_down(s, off);
    ss += __shfl_down(ss, off);
  }
  __shared__ float red[8];
  const int lane = threadIdx.x & 63, w = threadIdx.x >> 6;
  if (lane == 0) { red[w] = s; red[4 + w] = ss; }
  __syncthreads();
  const float stot = red[0] + red[1] + red[2] + red[3];
  const float sstot = red[4] + red[5] + red[6] + red[7];
  const float mu = stot * (1.0f / H_DIM);
  const float var = fmaxf(sstot * (1.0f / H_DIM) - mu * mu, 0.f);
  const float rs = rsqrtf(var + 1e-12f);
  const float4 g = *reinterpret_cast<const float4*>(gamma + threadIdx.x * 4);
  const float4 b = *reinterpret_cast<const float4*>(beta + threadIdx.x * 4);
  float4 o;
  o.x = (v.x - mu) * rs * g.x + b.x;
  o.y = (v.y - mu) * rs * g.y + b.y;
  o.z = (v.z - mu) * rs * g.z + b.z;
  o.w = (v.w - mu) * rs * g.w + b.w;
  *reinterpret_cast<float4*>(y + base) = o;
}

extern "C" void kernel_launch(void* const* d_in, const int* in_sizes, int n_in,
                              void* d_out, int out_size, void* d_ws, size_t ws_size,
                              hipStream_t stream) {
  const float* hidden = (const float*)d_in[0];
  const float* resid  = (const float*)d_in[1];
  const float* weight = (const float*)d_in[2];
  const float* bias   = (const float*)d_in[3];
  const float* gamma  = (const float*)d_in[4];
  const float* beta   = (const float*)d_in[5];
  float* out = (float*)d_out;

  const long nh = (long)in_sizes[0];   // B*S*H
  const int M = (int)(nh / H_DIM);     // 32768

  float* scales = (float*)d_ws;                               // [0]=amax_h,[1]=amax_w
  unsigned short* Wq = (unsigned short*)((char*)d_ws + 256);  // 2 MB
  unsigned short* Aq = Wq + (size_t)H_DIM * H_DIM;            // 67 MB
  unsigned short* ybf = Aq + (size_t)nh;                      // 67 MB
  const size_t need1 = 256 + (size_t)H_DIM * H_DIM * 2 + (size_t)nh * 4;
  const size_t need2 = 256 + (size_t)H_DIM * H_DIM * 2 + (size_t)nh * 2;

  hipMemsetAsync(d_ws, 0, 8, stream);
  absmax_clip_kernel<<<2048, 256, 0, stream>>>(hidden, nh, scales + 0);
  absmax_clip_kernel<<<256, 256, 0, stream>>>(weight, (long)H_DIM * H_DIM, scales + 1);
  quant_kernel<<<1024, 256, 0, stream>>>(weight, Wq, scales + 1, (long)H_DIM * H_DIM);

  if (ws_size >= need1 && (M % BMs) == 0 && (M % 2) == 0) {
    quant_kernel<<<2048, 256, 0, stream>>>(hidden, Aq, scales + 0, nh);
    gemm_s_kernel<<<(M / BMs) * (H_DIM / BNs), 256, 0, stream>>>(
        Aq, Wq, bias, resid, scales, ybf, M);
    ln_bf16_kernel<<<M / 2, 256, 0, stream>>>(ybf, gamma, beta, out);
  } else if (ws_size >= need2 && (M % BMv) == 0 && (M % 2) == 0) {
    unsigned short* ybf2 = Aq;  // reuse slot
    gemm_fa_kernel<<<(M / BMv) * (H_DIM / BNv), 256, 0, stream>>>(
        hidden, Wq, bias, resid, scales, ybf2, M);
    ln_bf16_kernel<<<M / 2, 256, 0, stream>>>(ybf2, gamma, beta, out);
  } else {
    gemm_fused_kernel<<<(M / BM) * (H_DIM / BN), 256, 0, stream>>>(
        hidden, Wq, bias, resid, scales, out, M);
    ln_kernel<<<M, 256, 0, stream>>>(out, gamma, beta);
  }
}

// Round 8
// 241.617 us; speedup vs baseline: 1.0256x; 1.0256x over previous
//
#include <hip/hip_runtime.h>
#include <hip/hip_bf16.h>
#include <stdint.h>

#define H_DIM 1024
#define QMAX 127.0f
#define CLIP 2.5f

typedef __attribute__((ext_vector_type(4))) float f32x4;
typedef __attribute__((ext_vector_type(8))) short bf16x8;
typedef __attribute__((ext_vector_type(8))) unsigned short u16x8;
typedef __attribute__((address_space(3))) void lds_void;
typedef const __attribute__((address_space(1))) void gmem_void;

// ---------------------------------------------------------------------------
// absmax of clip(x,-CLIP,CLIP) (n%4==0), atomicMax into *out (pre-zeroed).
// ---------------------------------------------------------------------------
__global__ __launch_bounds__(256) void absmax_clip_kernel(
    const float* __restrict__ x, long n, float* __restrict__ out) {
  float m = 0.f;
  const long stride = (long)gridDim.x * blockDim.x * 4;
  for (long i = ((long)blockIdx.x * blockDim.x + threadIdx.x) * 4; i < n; i += stride) {
    const float4 v = *reinterpret_cast<const float4*>(x + i);
    m = fmaxf(m, fmaxf(fmaxf(fabsf(v.x), fabsf(v.y)), fmaxf(fabsf(v.z), fabsf(v.w))));
  }
  m = fminf(m, CLIP);
#pragma unroll
  for (int off = 32; off > 0; off >>= 1) m = fmaxf(m, __shfl_down(m, off));
  __shared__ float red[4];
  const int lane = threadIdx.x & 63, w = threadIdx.x >> 6;
  if (lane == 0) red[w] = m;
  __syncthreads();
  if (threadIdx.x == 0) {
    const float mm = fmaxf(fmaxf(red[0], red[1]), fmaxf(red[2], red[3]));
    atomicMax(reinterpret_cast<unsigned int*>(out), __float_as_uint(mm));
  }
}

__device__ __forceinline__ unsigned short quant_bf16(float x, float s) {
  // round(clip(x)*s) is an integer in [-127,127] -> exact in bf16.
  const float q = rintf(fminf(fmaxf(x, -CLIP), CLIP) * s);
  return (unsigned short)(__float_as_uint(q) >> 16);
}

__device__ __forceinline__ unsigned short f2bf_rne(float f) {
  const unsigned u = __float_as_uint(f);
  return (unsigned short)((u + 0x7FFFu + ((u >> 16) & 1u)) >> 16);
}

__device__ __forceinline__ float bf2f(unsigned short u) {
  return __uint_as_float((unsigned)u << 16);
}

// ---------------------------------------------------------------------------
// Quantize fp32 -> bf16 integer values (grid-stride, n%4==0).
// ---------------------------------------------------------------------------
__global__ __launch_bounds__(256) void quant_kernel(
    const float* __restrict__ x, unsigned short* __restrict__ q,
    const float* __restrict__ amax_p, long n) {
  const float s = QMAX / fmaxf(amax_p[0], 1e-8f);
  const long stride = (long)gridDim.x * blockDim.x * 4;
  for (long i = ((long)blockIdx.x * blockDim.x + threadIdx.x) * 4; i < n; i += stride) {
    const float4 v = *reinterpret_cast<const float4*>(x + i);
    ushort4 o;
    o.x = quant_bf16(v.x, s);
    o.y = quant_bf16(v.y, s);
    o.z = quant_bf16(v.z, s);
    o.w = quant_bf16(v.w, s);
    *reinterpret_cast<ushort4*>(q + i) = o;
  }
}

// ===========================================================================
// gemm_s: pre-quantized GEMM, NO residual. gbf[m][n] = bf16(dot*inv_s + b[n])
// 128x128 tile, BK=32, 256 thr (4 waves 2x2), 16x16x32 MFMA, 4x4 frags/wave.
// K-loop: TRIPLE-buffered, ONE barrier/iter, counted vmcnt, stage-at-bottom:
//   [iter it] vmcnt(4) ; s_barrier ; ds_read buf[it%3] + MFMA ;
//             stage buf[(it+2)%3]
// Ledger: (RAW) each wave's vmcnt(4) retires its own tile-it loads; barrier
// makes it collective. (WAR) readers of buf[(it-1)%3] retired their ds_reads
// before reaching iter-it's barrier (lgkmcnt forced by MFMA use); the
// overwrite is issued after that barrier. Tile it+2 gets ~2 phases to land.
// Swizzled staging/reads (0-conflict, r3/r5/r6-verified). Epilogue: bf16 LDS
// bounce -> 16B-coalesced stores (r5/r6-verified).  LDS 48 KB -> 3 blocks/CU.
// ===========================================================================
#define BMs 128
#define BNs 128
#define BKs 32
#define NITs (H_DIM / BKs)

__global__ __launch_bounds__(256) void gemm_s_kernel(
    const unsigned short* __restrict__ Aq,   // [M][1024] bf16 ints
    const unsigned short* __restrict__ Wq,   // [1024][1024] bf16 ints
    const float* __restrict__ bias,
    const float* __restrict__ scales,
    unsigned short* __restrict__ gbf, int M) {
  // SM: K-loop uses [0..24575] (As 3x4096 @0, Bs 3x4096 @12288); epilogue
  // bounce reuses [0..17407] as 128 rows x 136 ushorts.
  __shared__ __attribute__((aligned(16))) unsigned short SM[24576];
  unsigned short* As = SM;           // [3][128*32]
  unsigned short* Bs = SM + 12288;   // [3][128*32]

  const int nwg = (M / BMs) * 8;
  const int orig = blockIdx.x;
  const int cpx = nwg >> 3;
  const int wg = ((nwg & 7) == 0) ? ((orig & 7) * cpx + (orig >> 3)) : orig;
  const int bn = wg & 7, bm = wg >> 3;      // bn fast -> A panel L2 reuse
  const int m0 = bm * BMs, n0 = bn * BNs;

  const int t = threadIdx.x;
  const int lane = t & 63, wid = t >> 6;
  const int wr = wid >> 1, wc = wid & 1;
  const int lrow = lane & 15, lgrp = lane >> 4;

  const float amax_h = fmaxf(scales[0], 1e-8f);
  const float amax_w = fmaxf(scales[1], 1e-8f);
  const float inv_s = (amax_h * amax_w) / (QMAX * QMAX);

  // staging: chunks c0=t, c1=t+256 -> row c>>2, 16B grp c&3; global source
  // col-group inverse-swizzled so swizzled reads see linear data.
  const int c0 = t, c1 = t + 256;
  const int r0 = c0 >> 2, r1 = c1 >> 2;
  const unsigned g0 = (unsigned)r0 * H_DIM + (unsigned)((((c0 & 3) ^ ((r0 >> 1) & 3))) * 8);
  const unsigned g1 = (unsigned)r1 * H_DIM + (unsigned)((((c1 & 3) ^ ((r1 >> 1) & 3))) * 8);
  const unsigned short* Ag = Aq + (size_t)m0 * H_DIM;
  const unsigned short* Bg = Wq + (size_t)n0 * H_DIM;

#define STAGE_T(BUF, KQ)                                                       \
  { __builtin_amdgcn_global_load_lds((gmem_void*)(Ag + g0 + (KQ)),             \
        (lds_void*)(As + (BUF)*4096 + c0 * 8), 16, 0, 0);                      \
    __builtin_amdgcn_global_load_lds((gmem_void*)(Ag + g1 + (KQ)),             \
        (lds_void*)(As + (BUF)*4096 + c1 * 8), 16, 0, 0);                      \
    __builtin_amdgcn_global_load_lds((gmem_void*)(Bg + g0 + (KQ)),             \
        (lds_void*)(Bs + (BUF)*4096 + c0 * 8), 16, 0, 0);                      \
    __builtin_amdgcn_global_load_lds((gmem_void*)(Bg + g1 + (KQ)),             \
        (lds_void*)(Bs + (BUF)*4096 + c1 * 8), 16, 0, 0); }

  // swizzled per-thread LDS read offsets (ushorts)
  int offA[4], offB[4];
#pragma unroll
  for (int i = 0; i < 4; ++i) {
    const int r = wr * 64 + i * 16 + lrow;
    offA[i] = r * 32 + ((lgrp ^ ((r >> 1) & 3)) * 8);
  }
#pragma unroll
  for (int j = 0; j < 4; ++j) {
    const int r = wc * 64 + j * 16 + lrow;
    offB[j] = r * 32 + ((lgrp ^ ((r >> 1) & 3)) * 8);
  }

  f32x4 acc[4][4];
#pragma unroll
  for (int i = 0; i < 4; i++)
#pragma unroll
    for (int j = 0; j < 4; j++)
#pragma unroll
      for (int r = 0; r < 4; r++) acc[i][j][r] = 0.f;

  // prologue: tiles 0 and 1 in flight (8 loads)
  STAGE_T(0, 0)
  STAGE_T(1, BKs)

  for (int it = 0; it < NITs; ++it) {
    const int cb = it % 3;
    if (it + 1 < NITs) {
      asm volatile("s_waitcnt vmcnt(4)" ::: "memory");  // own tile-it loads done
    } else {
      asm volatile("s_waitcnt vmcnt(0)" ::: "memory");  // drain final tile
    }
    __builtin_amdgcn_s_barrier();                        // collective: tile it ready

    bf16x8 af[4], bfr[4];
#pragma unroll
    for (int i = 0; i < 4; ++i)
      af[i] = *reinterpret_cast<const bf16x8*>(As + cb * 4096 + offA[i]);
#pragma unroll
    for (int j = 0; j < 4; ++j)
      bfr[j] = *reinterpret_cast<const bf16x8*>(Bs + cb * 4096 + offB[j]);
    __builtin_amdgcn_s_setprio(1);
#pragma unroll
    for (int i = 0; i < 4; ++i)
#pragma unroll
      for (int j = 0; j < 4; ++j)
        acc[i][j] = __builtin_amdgcn_mfma_f32_16x16x32_bf16(af[i], bfr[j], acc[i][j], 0, 0, 0);
    __builtin_amdgcn_s_setprio(0);

    if (it + 2 < NITs) {
      STAGE_T((it + 2) % 3, (unsigned)((it + 2) * BKs))  // overwrite buf[(it-1)%3]
    }
  }
#undef STAGE_T
  __syncthreads();  // all waves done with last tile before bounce overwrites LDS

  // epilogue: g = bf16(acc*inv_s + bias) -> LDS bounce -> coalesced stores
#pragma unroll
  for (int j = 0; j < 4; ++j) {
    const int cl = wc * 64 + j * 16 + lrow;
    const float bv = bias[n0 + cl];
#pragma unroll
    for (int i = 0; i < 4; ++i) {
      const int rl0 = wr * 64 + i * 16 + lgrp * 4;
#pragma unroll
      for (int r = 0; r < 4; ++r)
        SM[(rl0 + r) * 136 + cl] = f2bf_rne(acc[i][j][r] * inv_s + bv);
    }
  }
  __syncthreads();
  {
    const int e_row = t >> 1, e_half = t & 1;
    unsigned short* dst = gbf + (size_t)(m0 + e_row) * H_DIM + n0 + e_half * 64;
    const unsigned short* src = SM + e_row * 136 + e_half * 64;
#pragma unroll
    for (int c = 0; c < 8; ++c)
      *reinterpret_cast<u16x8*>(dst + c * 8) =
          *reinterpret_cast<const u16x8*>(src + c * 8);
  }
}

// ---------------------------------------------------------------------------
// ln_resid: y = bf16 g + fp32 resid; LayerNorm(y) -> fp32 out.
// 2 rows per block (256 thr), 8 cols/thread -> all accesses >=16B coalesced.
// ---------------------------------------------------------------------------
__global__ __launch_bounds__(256) void ln_resid_kernel(
    const unsigned short* __restrict__ gbf, const float* __restrict__ resid,
    const float* __restrict__ gamma, const float* __restrict__ beta,
    float* __restrict__ out) {
  const int rl = threadIdx.x >> 7;            // row within block (0/1)
  const int c0 = (threadIdx.x & 127) * 8;     // 8 cols per thread
  const size_t base = ((size_t)blockIdx.x * 2 + rl) * H_DIM + c0;

  const u16x8 g = *reinterpret_cast<const u16x8*>(gbf + base);
  const float4 rA = *reinterpret_cast<const float4*>(resid + base);
  const float4 rB = *reinterpret_cast<const float4*>(resid + base + 4);
  float v[8];
  v[0] = bf2f(g[0]) + rA.x; v[1] = bf2f(g[1]) + rA.y;
  v[2] = bf2f(g[2]) + rA.z; v[3] = bf2f(g[3]) + rA.w;
  v[4] = bf2f(g[4]) + rB.x; v[5] = bf2f(g[5]) + rB.y;
  v[6] = bf2f(g[6]) + rB.z; v[7] = bf2f(g[7]) + rB.w;

  float s = 0.f, ss = 0.f;
#pragma unroll
  for (int k = 0; k < 8; ++k) { s += v[k]; ss += v[k] * v[k]; }
#pragma unroll
  for (int off = 32; off > 0; off >>= 1) {
    s += __shfl_down(s, off);
    ss += __shfl_down(ss, off);
  }
  __shared__ float red[4][2];
  const int lane = threadIdx.x & 63, w = threadIdx.x >> 6;  // waves 0,1->row0; 2,3->row1
  if (lane == 0) { red[w][0] = s; red[w][1] = ss; }
  __syncthreads();
  const int wp = rl * 2;
  const float stot = red[wp][0] + red[wp + 1][0];
  const float sstot = red[wp][1] + red[wp + 1][1];
  const float mu = stot * (1.0f / H_DIM);
  const float var = fmaxf(sstot * (1.0f / H_DIM) - mu * mu, 0.f);
  const float rs = rsqrtf(var + 1e-12f);

  const float4 gA = *reinterpret_cast<const float4*>(gamma + c0);
  const float4 gB = *reinterpret_cast<const float4*>(gamma + c0 + 4);
  const float4 bA = *reinterpret_cast<const float4*>(beta + c0);
  const float4 bB = *reinterpret_cast<const float4*>(beta + c0 + 4);
  float4 oA, oB;
  oA.x = (v[0] - mu) * rs * gA.x + bA.x;
  oA.y = (v[1] - mu) * rs * gA.y + bA.y;
  oA.z = (v[2] - mu) * rs * gA.z + bA.z;
  oA.w = (v[3] - mu) * rs * gA.w + bA.w;
  oB.x = (v[4] - mu) * rs * gB.x + bB.x;
  oB.y = (v[5] - mu) * rs * gB.y + bB.y;
  oB.z = (v[6] - mu) * rs * gB.z + bB.z;
  oB.w = (v[7] - mu) * rs * gB.w + bB.w;
  *reinterpret_cast<float4*>(out + base) = oA;
  *reinterpret_cast<float4*>(out + base + 4) = oB;
}

// ===========================================================================
// Tier-2 fallback (round-5 validated): fused-quant GEMM + resid -> ybf.
// ===========================================================================
#define BMv 128
#define BNv 128
#define BKv 32

__global__ __launch_bounds__(256) void gemm_fa_kernel(
    const float* __restrict__ hidden, const unsigned short* __restrict__ Wq,
    const float* __restrict__ bias, const float* __restrict__ resid,
    const float* __restrict__ scales, unsigned short* __restrict__ ybf, int M) {
  __shared__ __attribute__((aligned(16))) unsigned short SM[17408];
  unsigned short* As = SM;
  unsigned short* Bs = SM + 8192;
  const int nwg = (M / BMv) * 8;
  const int orig = blockIdx.x;
  const int cpx = nwg >> 3;
  const int wg = ((nwg & 7) == 0) ? ((orig & 7) * cpx + (orig >> 3)) : orig;
  const int bn = wg & 7, bm = wg >> 3;
  const int m0 = bm * BMv, n0 = bn * BNv;
  const int t = threadIdx.x;
  const int lane = t & 63, wid = t >> 6;
  const int wr = wid >> 1, wc = wid & 1;
  const int lrow = lane & 15, lgrp = lane >> 4;
  const float amax_h = fmaxf(scales[0], 1e-8f);
  const float amax_w = fmaxf(scales[1], 1e-8f);
  const float sh = QMAX / amax_h;
  const float inv_s = (amax_h * amax_w) / (QMAX * QMAX);
  const int a_row = t >> 1, a_half = t & 1;
  const float* Ag = hidden + (size_t)(m0 + a_row) * H_DIM + a_half * 16;
  const int a_swz = (a_row >> 1) & 3;
  const int aw0 = a_row * 32 + (((a_half * 2 + 0) ^ a_swz) * 8);
  const int aw1 = a_row * 32 + (((a_half * 2 + 1) ^ a_swz) * 8);
  const int bc0 = t, bc1 = t + 256;
  const int br0 = bc0 >> 2, br1 = bc1 >> 2;
  const unsigned bg0 = (unsigned)br0 * H_DIM + (unsigned)((((bc0 & 3) ^ ((br0 >> 1) & 3))) * 8);
  const unsigned bg1 = (unsigned)br1 * H_DIM + (unsigned)((((bc1 & 3) ^ ((br1 >> 1) & 3))) * 8);
  const unsigned short* Bg = Wq + (size_t)n0 * H_DIM;
  int offA[4], offB[4];
#pragma unroll
  for (int i = 0; i < 4; ++i) {
    const int r = wr * 64 + i * 16 + lrow;
    offA[i] = r * 32 + ((lgrp ^ ((r >> 1) & 3)) * 8);
  }
#pragma unroll
  for (int j = 0; j < 4; ++j) {
    const int r = wc * 64 + j * 16 + lrow;
    offB[j] = r * 32 + ((lgrp ^ ((r >> 1) & 3)) * 8);
  }
  f32x4 acc[4][4];
#pragma unroll
  for (int i = 0; i < 4; i++)
#pragma unroll
    for (int j = 0; j < 4; j++)
#pragma unroll
      for (int r = 0; r < 4; r++) acc[i][j][r] = 0.f;
#define QUANT_PACK(dst0, dst1, v0, v1, v2, v3)                                 \
  {                                                                            \
    u16x8 p0, p1;                                                              \
    p0[0] = quant_bf16((v0).x, sh); p0[1] = quant_bf16((v0).y, sh);            \
    p0[2] = quant_bf16((v0).z, sh); p0[3] = quant_bf16((v0).w, sh);            \
    p0[4] = quant_bf16((v1).x, sh); p0[5] = quant_bf16((v1).y, sh);            \
    p0[6] = quant_bf16((v1).z, sh); p0[7] = quant_bf16((v1).w, sh);            \
    p1[0] = quant_bf16((v2).x, sh); p1[1] = quant_bf16((v2).y, sh);            \
    p1[2] = quant_bf16((v2).z, sh); p1[3] = quant_bf16((v2).w, sh);            \
    p1[4] = quant_bf16((v3).x, sh); p1[5] = quant_bf16((v3).y, sh);            \
    p1[6] = quant_bf16((v3).z, sh); p1[7] = quant_bf16((v3).w, sh);            \
    *reinterpret_cast<u16x8*>(dst0) = p0;                                      \
    *reinterpret_cast<u16x8*>(dst1) = p1;                                      \
  }
  {
    const float4 v0 = *reinterpret_cast<const float4*>(Ag + 0);
    const float4 v1 = *reinterpret_cast<const float4*>(Ag + 4);
    const float4 v2 = *reinterpret_cast<const float4*>(Ag + 8);
    const float4 v3 = *reinterpret_cast<const float4*>(Ag + 12);
    __builtin_amdgcn_global_load_lds((gmem_void*)(Bg + bg0), (lds_void*)(Bs + bc0 * 8), 16, 0, 0);
    __builtin_amdgcn_global_load_lds((gmem_void*)(Bg + bg1), (lds_void*)(Bs + bc1 * 8), 16, 0, 0);
    QUANT_PACK(As + aw0, As + aw1, v0, v1, v2, v3)
    __syncthreads();
  }
  for (int it = 0; it < H_DIM / BKv; ++it) {
    const int cur = it & 1, nxt = cur ^ 1;
    const bool more = (it + 1) < (H_DIM / BKv);
    float4 v0, v1, v2, v3;
    if (more) {
      const float* Agn = Ag + (it + 1) * BKv;
      v0 = *reinterpret_cast<const float4*>(Agn + 0);
      v1 = *reinterpret_cast<const float4*>(Agn + 4);
      v2 = *reinterpret_cast<const float4*>(Agn + 8);
      v3 = *reinterpret_cast<const float4*>(Agn + 12);
      const unsigned kq = (unsigned)((it + 1) * BKv);
      __builtin_amdgcn_global_load_lds((gmem_void*)(Bg + bg0 + kq),
                                       (lds_void*)(Bs + nxt * 4096 + bc0 * 8), 16, 0, 0);
      __builtin_amdgcn_global_load_lds((gmem_void*)(Bg + bg1 + kq),
                                       (lds_void*)(Bs + nxt * 4096 + bc1 * 8), 16, 0, 0);
    }
    bf16x8 af[4], bfr[4];
#pragma unroll
    for (int i = 0; i < 4; ++i)
      af[i] = *reinterpret_cast<const bf16x8*>(As + cur * 4096 + offA[i]);
#pragma unroll
    for (int j = 0; j < 4; ++j)
      bfr[j] = *reinterpret_cast<const bf16x8*>(Bs + cur * 4096 + offB[j]);
    __builtin_amdgcn_s_setprio(1);
#pragma unroll
    for (int i = 0; i < 4; ++i)
#pragma unroll
      for (int j = 0; j < 4; ++j)
        acc[i][j] = __builtin_amdgcn_mfma_f32_16x16x32_bf16(af[i], bfr[j], acc[i][j], 0, 0, 0);
    __builtin_amdgcn_s_setprio(0);
    if (more) {
      QUANT_PACK(As + nxt * 4096 + aw0, As + nxt * 4096 + aw1, v0, v1, v2, v3)
    }
    __syncthreads();
  }
#pragma unroll
  for (int j = 0; j < 4; ++j) {
    const int cl = wc * 64 + j * 16 + lrow;
    const float bv = bias[n0 + cl];
#pragma unroll
    for (int i = 0; i < 4; ++i) {
      const int rl0 = wr * 64 + i * 16 + lgrp * 4;
#pragma unroll
      for (int r = 0; r < 4; ++r) {
        const float y = acc[i][j][r] * inv_s + bv +
                        resid[(size_t)(m0 + rl0 + r) * H_DIM + n0 + cl];
        SM[(rl0 + r) * 136 + cl] = f2bf_rne(y);
      }
    }
  }
  __syncthreads();
  {
    const int e_row = t >> 1, e_half = t & 1;
    unsigned short* dst = ybf + (size_t)(m0 + e_row) * H_DIM + n0 + e_half * 64;
    const unsigned short* src = SM + e_row * 136 + e_half * 64;
#pragma unroll
    for (int c = 0; c < 8; ++c)
      *reinterpret_cast<u16x8*>(dst + c * 8) =
          *reinterpret_cast<const u16x8*>(src + c * 8);
  }
#undef QUANT_PACK
}

__global__ __launch_bounds__(256) void ln_bf16_kernel(
    const unsigned short* __restrict__ ybf, const float* __restrict__ gamma,
    const float* __restrict__ beta, float* __restrict__ out) {
  const size_t base = (size_t)blockIdx.x * H_DIM + threadIdx.x * 4;
  const ushort4 u = *reinterpret_cast<const ushort4*>(ybf + base);
  float4 v;
  v.x = bf2f(u.x); v.y = bf2f(u.y); v.z = bf2f(u.z); v.w = bf2f(u.w);
  float s = v.x + v.y + v.z + v.w;
  float ss = v.x * v.x + v.y * v.y + v.z * v.z + v.w * v.w;
#pragma unroll
  for (int off = 32; off > 0; off >>= 1) {
    s += __shfl_down(s, off);
    ss += __shfl_down(ss, off);
  }
  __shared__ float red[8];
  const int lane = threadIdx.x & 63, w = threadIdx.x >> 6;
  if (lane == 0) { red[w] = s; red[4 + w] = ss; }
  __syncthreads();
  const float stot = red[0] + red[1] + red[2] + red[3];
  const float sstot = red[4] + red[5] + red[6] + red[7];
  const float mu = stot * (1.0f / H_DIM);
  const float var = fmaxf(sstot * (1.0f / H_DIM) - mu * mu, 0.f);
  const float rs = rsqrtf(var + 1e-12f);
  const float4 g = *reinterpret_cast<const float4*>(gamma + threadIdx.x * 4);
  const float4 b = *reinterpret_cast<const float4*>(beta + threadIdx.x * 4);
  float4 o;
  o.x = (v.x - mu) * rs * g.x + b.x;
  o.y = (v.y - mu) * rs * g.y + b.y;
  o.z = (v.z - mu) * rs * g.z + b.z;
  o.w = (v.w - mu) * rs * g.w + b.w;
  *reinterpret_cast<float4*>(out + base) = o;
}

// ===========================================================================
// Tier-3 fallback (round-1 validated).
// ===========================================================================
#define BM 128
#define BN 128
#define BK 32

__global__ __launch_bounds__(256, 2) void gemm_fused_kernel(
    const float* __restrict__ A, const unsigned short* __restrict__ Wq,
    const float* __restrict__ bias, const float* __restrict__ resid,
    const float* __restrict__ scales, float* __restrict__ out, int M) {
  __shared__ unsigned short Asf[BM][40];
  __shared__ unsigned short Bsf[BN][40];
  const int nbm = M / BM;
  const int bm = blockIdx.x % nbm, bn = blockIdx.x / nbm;
  const int m0 = bm * BM, n0 = bn * BN;
  const int t = threadIdx.x;
  const int lane = t & 63, wid = t >> 6;
  const int wr = wid >> 1, wc = wid & 1;
  const int lrow = lane & 15, lgrp = lane >> 4;
  const float amax_h = fmaxf(scales[0], 1e-8f);
  const float amax_w = fmaxf(scales[1], 1e-8f);
  const float sh = QMAX / amax_h;
  const float inv_s = (amax_h * amax_w) / (QMAX * QMAX);
  f32x4 acc[4][4];
#pragma unroll
  for (int i = 0; i < 4; i++)
#pragma unroll
    for (int j = 0; j < 4; j++)
#pragma unroll
      for (int r = 0; r < 4; r++) acc[i][j][r] = 0.f;
  for (int k0 = 0; k0 < H_DIM; k0 += BK) {
#pragma unroll
    for (int j = 0; j < 4; ++j) {
      const int f = j * 256 + t;
      const int r = f >> 3, c4 = f & 7;
      const float4 v = *reinterpret_cast<const float4*>(A + (size_t)(m0 + r) * H_DIM + k0 + c4 * 4);
      ushort4 q;
      q.x = quant_bf16(v.x, sh); q.y = quant_bf16(v.y, sh);
      q.z = quant_bf16(v.z, sh); q.w = quant_bf16(v.w, sh);
      *reinterpret_cast<ushort4*>(&Asf[r][c4 * 4]) = q;
    }
#pragma unroll
    for (int j = 0; j < 2; ++j) {
      const int f = j * 256 + t;
      const int r = f >> 2, cb = f & 3;
      const uint4 v = *reinterpret_cast<const uint4*>(Wq + (size_t)(n0 + r) * H_DIM + k0 + cb * 8);
      *reinterpret_cast<uint4*>(&Bsf[r][cb * 8]) = v;
    }
    __syncthreads();
    bf16x8 af[4], bfr[4];
#pragma unroll
    for (int i = 0; i < 4; i++)
      af[i] = *reinterpret_cast<const bf16x8*>(&Asf[wr * 64 + i * 16 + lrow][lgrp * 8]);
#pragma unroll
    for (int j = 0; j < 4; j++)
      bfr[j] = *reinterpret_cast<const bf16x8*>(&Bsf[wc * 64 + j * 16 + lrow][lgrp * 8]);
#pragma unroll
    for (int i = 0; i < 4; i++)
#pragma unroll
      for (int j = 0; j < 4; j++)
        acc[i][j] = __builtin_amdgcn_mfma_f32_16x16x32_bf16(af[i], bfr[j], acc[i][j], 0, 0, 0);
    __syncthreads();
  }
#pragma unroll
  for (int j = 0; j < 4; j++) {
    const int col = n0 + wc * 64 + j * 16 + lrow;
    const float bv = bias[col];
#pragma unroll
    for (int i = 0; i < 4; i++) {
      const int row0 = m0 + wr * 64 + i * 16 + lgrp * 4;
#pragma unroll
      for (int r = 0; r < 4; r++) {
        const size_t off = (size_t)(row0 + r) * H_DIM + col;
        out[off] = acc[i][j][r] * inv_s + bv + resid[off];
      }
    }
  }
}

__global__ __launch_bounds__(256) void ln_kernel(
    float* __restrict__ y, const float* __restrict__ gamma,
    const float* __restrict__ beta) {
  const size_t base = (size_t)blockIdx.x * H_DIM + threadIdx.x * 4;
  const float4 v = *reinterpret_cast<const float4*>(y + base);
  float s = v.x + v.y + v.z + v.w;
  float ss = v.x * v.x + v.y * v.y + v.z * v.z + v.w * v.w;
#pragma unroll
  for (int off = 32; off > 0; off >>= 1) {
    s += __shfl_down(s, off);
    ss += __shfl_down(ss, off);
  }
  __shared__ float red[8];
  const int lane = threadIdx.x & 63, w = threadIdx.x >> 6;
  if (lane == 0) { red[w] = s; red[4 + w] = ss; }
  __syncthreads();
  const float stot = red[0] + red[1] + red[2] + red[3];
  const float sstot = red[4] + red[5] + red[6] + red[7];
  const float mu = stot * (1.0f / H_DIM);
  const float var = fmaxf(sstot * (1.0f / H_DIM) - mu * mu, 0.f);
  const float rs = rsqrtf(var + 1e-12f);
  const float4 g = *reinterpret_cast<const float4*>(gamma + threadIdx.x * 4);
  const float4 b = *reinterpret_cast<const float4*>(beta + threadIdx.x * 4);
  float4 o;
  o.x = (v.x - mu) * rs * g.x + b.x;
  o.y = (v.y - mu) * rs * g.y + b.y;
  o.z = (v.z - mu) * rs * g.z + b.z;
  o.w = (v.w - mu) * rs * g.w + b.w;
  *reinterpret_cast<float4*>(y + base) = o;
}

extern "C" void kernel_launch(void* const* d_in, const int* in_sizes, int n_in,
                              void* d_out, int out_size, void* d_ws, size_t ws_size,
                              hipStream_t stream) {
  const float* hidden = (const float*)d_in[0];
  const float* resid  = (const float*)d_in[1];
  const float* weight = (const float*)d_in[2];
  const float* bias   = (const float*)d_in[3];
  const float* gamma  = (const float*)d_in[4];
  const float* beta   = (const float*)d_in[5];
  float* out = (float*)d_out;

  const long nh = (long)in_sizes[0];   // B*S*H
  const int M = (int)(nh / H_DIM);     // 32768

  float* scales = (float*)d_ws;                               // [0]=amax_h,[1]=amax_w
  unsigned short* Wq = (unsigned short*)((char*)d_ws + 256);  // 2 MB
  unsigned short* Aq = Wq + (size_t)H_DIM * H_DIM;            // 67 MB
  unsigned short* gbf = Aq + (size_t)nh;                      // 67 MB
  const size_t need1 = 256 + (size_t)H_DIM * H_DIM * 2 + (size_t)nh * 4;
  const size_t need2 = 256 + (size_t)H_DIM * H_DIM * 2 + (size_t)nh * 2;

  hipMemsetAsync(d_ws, 0, 8, stream);
  absmax_clip_kernel<<<2048, 256, 0, stream>>>(hidden, nh, scales + 0);
  absmax_clip_kernel<<<256, 256, 0, stream>>>(weight, (long)H_DIM * H_DIM, scales + 1);
  quant_kernel<<<1024, 256, 0, stream>>>(weight, Wq, scales + 1, (long)H_DIM * H_DIM);

  if (ws_size >= need1 && (M % BMs) == 0 && (M % 2) == 0) {
    quant_kernel<<<2048, 256, 0, stream>>>(hidden, Aq, scales + 0, nh);
    gemm_s_kernel<<<(M / BMs) * (H_DIM / BNs), 256, 0, stream>>>(
        Aq, Wq, bias, scales, gbf, M);
    ln_resid_kernel<<<M / 2, 256, 0, stream>>>(gbf, resid, gamma, beta, out);
  } else if (ws_size >= need2 && (M % BMv) == 0) {
    unsigned short* ybf = Aq;  // reuse slot
    gemm_fa_kernel<<<(M / BMv) * (H_DIM / BNv), 256, 0, stream>>>(
        hidden, Wq, bias, resid, scales, ybf, M);
    ln_bf16_kernel<<<M, 256, 0, stream>>>(ybf, gamma, beta, out);
  } else {
    gemm_fused_kernel<<<(M / BM) * (H_DIM / BN), 256, 0, stream>>>(
        hidden, Wq, bias, resid, scales, out, M);
    ln_kernel<<<M, 256, 0, stream>>>(out, gamma, beta);
  }
}

// Round 9
// 198.102 us; speedup vs baseline: 1.2509x; 1.2197x over previous
//
#include <hip/hip_runtime.h>
#include <hip/hip_bf16.h>
#include <stdint.h>

#define H_DIM 1024
#define QMAX 127.0f
#define CLIP 2.5f

typedef __attribute__((ext_vector_type(4))) float f32x4;
typedef __attribute__((ext_vector_type(4))) int i32x4;
typedef __attribute__((ext_vector_type(8))) short bf16x8;
typedef __attribute__((ext_vector_type(8))) unsigned short u16x8;
typedef __attribute__((address_space(3))) void lds_void;
typedef const __attribute__((address_space(1))) void gmem_void;

// ---------------------------------------------------------------------------
// absmax of clip(x,-CLIP,CLIP) (n%4==0), atomicMax into *out (pre-zeroed).
// ---------------------------------------------------------------------------
__global__ __launch_bounds__(256) void absmax_clip_kernel(
    const float* __restrict__ x, long n, float* __restrict__ out) {
  float m = 0.f;
  const long stride = (long)gridDim.x * blockDim.x * 4;
  for (long i = ((long)blockIdx.x * blockDim.x + threadIdx.x) * 4; i < n; i += stride) {
    const float4 v = *reinterpret_cast<const float4*>(x + i);
    m = fmaxf(m, fmaxf(fmaxf(fabsf(v.x), fabsf(v.y)), fmaxf(fabsf(v.z), fabsf(v.w))));
  }
  m = fminf(m, CLIP);
#pragma unroll
  for (int off = 32; off > 0; off >>= 1) m = fmaxf(m, __shfl_down(m, off));
  __shared__ float red[4];
  const int lane = threadIdx.x & 63, w = threadIdx.x >> 6;
  if (lane == 0) red[w] = m;
  __syncthreads();
  if (threadIdx.x == 0) {
    const float mm = fmaxf(fmaxf(red[0], red[1]), fmaxf(red[2], red[3]));
    atomicMax(reinterpret_cast<unsigned int*>(out), __float_as_uint(mm));
  }
}

__device__ __forceinline__ unsigned short quant_bf16(float x, float s) {
  const float q = rintf(fminf(fmaxf(x, -CLIP), CLIP) * s);
  return (unsigned short)(__float_as_uint(q) >> 16);
}

__device__ __forceinline__ int quant_i8(float x, float s) {
  return (int)rintf(fminf(fmaxf(x, -CLIP), CLIP) * s);  // in [-127,127]
}

__device__ __forceinline__ unsigned short f2bf_rne(float f) {
  const unsigned u = __float_as_uint(f);
  return (unsigned short)((u + 0x7FFFu + ((u >> 16) & 1u)) >> 16);
}

__device__ __forceinline__ float bf2f(unsigned short u) {
  return __uint_as_float((unsigned)u << 16);
}

// ---------------------------------------------------------------------------
// Quantize fp32 -> bf16 integer values (fallback paths).
// ---------------------------------------------------------------------------
__global__ __launch_bounds__(256) void quant_kernel(
    const float* __restrict__ x, unsigned short* __restrict__ q,
    const float* __restrict__ amax_p, long n) {
  const float s = QMAX / fmaxf(amax_p[0], 1e-8f);
  const long stride = (long)gridDim.x * blockDim.x * 4;
  for (long i = ((long)blockIdx.x * blockDim.x + threadIdx.x) * 4; i < n; i += stride) {
    const float4 v = *reinterpret_cast<const float4*>(x + i);
    ushort4 o;
    o.x = quant_bf16(v.x, s);
    o.y = quant_bf16(v.y, s);
    o.z = quant_bf16(v.z, s);
    o.w = quant_bf16(v.w, s);
    *reinterpret_cast<ushort4*>(q + i) = o;
  }
}

// ---------------------------------------------------------------------------
// Quantize fp32 -> int8 (grid-stride, n%8==0). 8 elems/thread, 8B stores.
// ---------------------------------------------------------------------------
__global__ __launch_bounds__(256) void quant8_kernel(
    const float* __restrict__ x, signed char* __restrict__ q,
    const float* __restrict__ amax_p, long n) {
  const float s = QMAX / fmaxf(amax_p[0], 1e-8f);
  const long stride = (long)gridDim.x * blockDim.x * 8;
  for (long i = ((long)blockIdx.x * blockDim.x + threadIdx.x) * 8; i < n; i += stride) {
    const float4 v0 = *reinterpret_cast<const float4*>(x + i);
    const float4 v1 = *reinterpret_cast<const float4*>(x + i + 4);
    unsigned r0 = ((unsigned)(unsigned char)(signed char)quant_i8(v0.x, s)) |
                  ((unsigned)(unsigned char)(signed char)quant_i8(v0.y, s) << 8) |
                  ((unsigned)(unsigned char)(signed char)quant_i8(v0.z, s) << 16) |
                  ((unsigned)(unsigned char)(signed char)quant_i8(v0.w, s) << 24);
    unsigned r1 = ((unsigned)(unsigned char)(signed char)quant_i8(v1.x, s)) |
                  ((unsigned)(unsigned char)(signed char)quant_i8(v1.y, s) << 8) |
                  ((unsigned)(unsigned char)(signed char)quant_i8(v1.z, s) << 16) |
                  ((unsigned)(unsigned char)(signed char)quant_i8(v1.w, s) << 24);
    uint2 o; o.x = r0; o.y = r1;
    *reinterpret_cast<uint2*>(q + i) = o;
  }
}

// ===========================================================================
// gemm_s8: int8 GEMM, NO residual. gbf[m][n] = bf16((i32 dot)*inv_s + b[n])
// 128x128 tile, BK=64 (16 iterations), 256 thr (4 waves 2x2),
// mfma_i32_16x16x64_i8 (4x4 frags/wave, one MFMA covers K=64).
// K-loop: triple-buffered, ONE barrier/iter, counted vmcnt, stage-at-bottom
// (r8-validated structure).  Tile byte-geometry identical to the bf16 case
// (row = 64 B = 4 x 16B chunks) -> same verified swizzle, 0 conflicts.
// Epilogue: cvt i32->f32 (exact: |dot| <= 1024*127^2 < 2^24), *inv_s + bias,
// bf16 LDS bounce -> 16B-coalesced stores (r5/r6-validated).
// LDS 48 KB -> 3 blocks/CU.
// ===========================================================================
#define BMs 128
#define BNs 128
#define BKs8 64
#define NIT8 (H_DIM / BKs8) /* 16 */

__global__ __launch_bounds__(256) void gemm_s8_kernel(
    const signed char* __restrict__ Aq8,   // [M][1024] i8
    const signed char* __restrict__ Wq8,   // [1024][1024] i8
    const float* __restrict__ bias,
    const float* __restrict__ scales,
    unsigned short* __restrict__ gbf, int M) {
  // SM8: K-loop uses [0..49151] (As 3x8192 @0, Bs 3x8192 @24576); epilogue
  // bounce reuses [0..34815] as 128 rows x 136 ushorts.
  __shared__ __attribute__((aligned(16))) char SM8[49152];
  char* As = SM8;            // [3][128*64] i8
  char* Bs = SM8 + 24576;    // [3][128*64] i8

  const int nwg = (M / BMs) * 8;
  const int orig = blockIdx.x;
  const int cpx = nwg >> 3;
  const int wg = ((nwg & 7) == 0) ? ((orig & 7) * cpx + (orig >> 3)) : orig;
  const int bn = wg & 7, bm = wg >> 3;      // bn fast -> A panel L2 reuse
  const int m0 = bm * BMs, n0 = bn * BNs;

  const int t = threadIdx.x;
  const int lane = t & 63, wid = t >> 6;
  const int wr = wid >> 1, wc = wid & 1;
  const int lrow = lane & 15, lgrp = lane >> 4;

  const float amax_h = fmaxf(scales[0], 1e-8f);
  const float amax_w = fmaxf(scales[1], 1e-8f);
  const float inv_s = (amax_h * amax_w) / (QMAX * QMAX);

  // staging: 512 16B chunks per 128x64 tile; chunk c -> row c>>2, grp c&3;
  // global source col-group inverse-swizzled (byte offsets).
  const int c0 = t, c1 = t + 256;
  const int r0 = c0 >> 2, r1 = c1 >> 2;
  const unsigned g0 = (unsigned)r0 * H_DIM + (unsigned)((((c0 & 3) ^ ((r0 >> 1) & 3))) * 16);
  const unsigned g1 = (unsigned)r1 * H_DIM + (unsigned)((((c1 & 3) ^ ((r1 >> 1) & 3))) * 16);
  const signed char* Ag = Aq8 + (size_t)m0 * H_DIM;
  const signed char* Bg = Wq8 + (size_t)n0 * H_DIM;

#define STAGE_T8(BUF, KQ)                                                      \
  { __builtin_amdgcn_global_load_lds((gmem_void*)(Ag + g0 + (KQ)),             \
        (lds_void*)(As + (BUF)*8192 + c0 * 16), 16, 0, 0);                     \
    __builtin_amdgcn_global_load_lds((gmem_void*)(Ag + g1 + (KQ)),             \
        (lds_void*)(As + (BUF)*8192 + c1 * 16), 16, 0, 0);                     \
    __builtin_amdgcn_global_load_lds((gmem_void*)(Bg + g0 + (KQ)),             \
        (lds_void*)(Bs + (BUF)*8192 + c0 * 16), 16, 0, 0);                     \
    __builtin_amdgcn_global_load_lds((gmem_void*)(Bg + g1 + (KQ)),             \
        (lds_void*)(Bs + (BUF)*8192 + c1 * 16), 16, 0, 0); }

  // per-thread swizzled LDS read offsets (bytes): lane (lrow,lgrp) reads
  // row r, k-bytes lgrp*16..+15 (k = lgrp*16 + elem for 16x16x64 i8).
  int offA[4], offB[4];
#pragma unroll
  for (int i = 0; i < 4; ++i) {
    const int r = wr * 64 + i * 16 + lrow;
    offA[i] = r * 64 + ((lgrp ^ ((r >> 1) & 3)) * 16);
  }
#pragma unroll
  for (int j = 0; j < 4; ++j) {
    const int r = wc * 64 + j * 16 + lrow;
    offB[j] = r * 64 + ((lgrp ^ ((r >> 1) & 3)) * 16);
  }

  i32x4 acc[4][4];
#pragma unroll
  for (int i = 0; i < 4; i++)
#pragma unroll
    for (int j = 0; j < 4; j++)
#pragma unroll
      for (int r = 0; r < 4; r++) acc[i][j][r] = 0;

  // prologue: tiles 0 and 1 in flight (8 loads)
  STAGE_T8(0, 0)
  STAGE_T8(1, BKs8)

  for (int it = 0; it < NIT8; ++it) {
    const int cb = it % 3;
    if (it + 1 < NIT8) {
      asm volatile("s_waitcnt vmcnt(4)" ::: "memory");  // own tile-it loads done
    } else {
      asm volatile("s_waitcnt vmcnt(0)" ::: "memory");  // drain final tile
    }
    __builtin_amdgcn_s_barrier();                        // collective: tile it ready

    i32x4 af[4], bfr[4];
#pragma unroll
    for (int i = 0; i < 4; ++i)
      af[i] = *reinterpret_cast<const i32x4*>(As + cb * 8192 + offA[i]);
#pragma unroll
    for (int j = 0; j < 4; ++j)
      bfr[j] = *reinterpret_cast<const i32x4*>(Bs + cb * 8192 + offB[j]);
    __builtin_amdgcn_s_setprio(1);
#pragma unroll
    for (int i = 0; i < 4; ++i)
#pragma unroll
      for (int j = 0; j < 4; ++j)
        acc[i][j] = __builtin_amdgcn_mfma_i32_16x16x64_i8(af[i], bfr[j], acc[i][j], 0, 0, 0);
    __builtin_amdgcn_s_setprio(0);

    if (it + 2 < NIT8) {
      STAGE_T8((it + 2) % 3, (unsigned)((it + 2) * BKs8))
    }
  }
#undef STAGE_T8
  __syncthreads();  // all waves done with last tile before bounce overwrites LDS

  // epilogue: g = bf16((float)acc*inv_s + bias) -> LDS bounce -> coalesced
  unsigned short* SMu = reinterpret_cast<unsigned short*>(SM8);
#pragma unroll
  for (int j = 0; j < 4; ++j) {
    const int cl = wc * 64 + j * 16 + lrow;
    const float bv = bias[n0 + cl];
#pragma unroll
    for (int i = 0; i < 4; ++i) {
      const int rl0 = wr * 64 + i * 16 + lgrp * 4;
#pragma unroll
      for (int r = 0; r < 4; ++r)
        SMu[(rl0 + r) * 136 + cl] = f2bf_rne((float)acc[i][j][r] * inv_s + bv);
    }
  }
  __syncthreads();
  {
    const int e_row = t >> 1, e_half = t & 1;
    unsigned short* dst = gbf + (size_t)(m0 + e_row) * H_DIM + n0 + e_half * 64;
    const unsigned short* src = SMu + e_row * 136 + e_half * 64;
#pragma unroll
    for (int c = 0; c < 8; ++c)
      *reinterpret_cast<u16x8*>(dst + c * 8) =
          *reinterpret_cast<const u16x8*>(src + c * 8);
  }
}

// ---------------------------------------------------------------------------
// ln_resid: y = bf16 g + fp32 resid; LayerNorm(y) -> fp32 out.
// 2 rows per block (256 thr), 8 cols/thread -> all accesses >=16B coalesced.
// ---------------------------------------------------------------------------
__global__ __launch_bounds__(256) void ln_resid_kernel(
    const unsigned short* __restrict__ gbf, const float* __restrict__ resid,
    const float* __restrict__ gamma, const float* __restrict__ beta,
    float* __restrict__ out) {
  const int rl = threadIdx.x >> 7;            // row within block (0/1)
  const int c0 = (threadIdx.x & 127) * 8;     // 8 cols per thread
  const size_t base = ((size_t)blockIdx.x * 2 + rl) * H_DIM + c0;

  const u16x8 g = *reinterpret_cast<const u16x8*>(gbf + base);
  const float4 rA = *reinterpret_cast<const float4*>(resid + base);
  const float4 rB = *reinterpret_cast<const float4*>(resid + base + 4);
  float v[8];
  v[0] = bf2f(g[0]) + rA.x; v[1] = bf2f(g[1]) + rA.y;
  v[2] = bf2f(g[2]) + rA.z; v[3] = bf2f(g[3]) + rA.w;
  v[4] = bf2f(g[4]) + rB.x; v[5] = bf2f(g[5]) + rB.y;
  v[6] = bf2f(g[6]) + rB.z; v[7] = bf2f(g[7]) + rB.w;

  float s = 0.f, ss = 0.f;
#pragma unroll
  for (int k = 0; k < 8; ++k) { s += v[k]; ss += v[k] * v[k]; }
#pragma unroll
  for (int off = 32; off > 0; off >>= 1) {
    s += __shfl_down(s, off);
    ss += __shfl_down(ss, off);
  }
  __shared__ float red[4][2];
  const int lane = threadIdx.x & 63, w = threadIdx.x >> 6;  // waves 0,1->row0; 2,3->row1
  if (lane == 0) { red[w][0] = s; red[w][1] = ss; }
  __syncthreads();
  const int wp = rl * 2;
  const float stot = red[wp][0] + red[wp + 1][0];
  const float sstot = red[wp][1] + red[wp + 1][1];
  const float mu = stot * (1.0f / H_DIM);
  const float var = fmaxf(sstot * (1.0f / H_DIM) - mu * mu, 0.f);
  const float rs = rsqrtf(var + 1e-12f);

  const float4 gA = *reinterpret_cast<const float4*>(gamma + c0);
  const float4 gB = *reinterpret_cast<const float4*>(gamma + c0 + 4);
  const float4 bA = *reinterpret_cast<const float4*>(beta + c0);
  const float4 bB = *reinterpret_cast<const float4*>(beta + c0 + 4);
  float4 oA, oB;
  oA.x = (v[0] - mu) * rs * gA.x + bA.x;
  oA.y = (v[1] - mu) * rs * gA.y + bA.y;
  oA.z = (v[2] - mu) * rs * gA.z + bA.z;
  oA.w = (v[3] - mu) * rs * gA.w + bA.w;
  oB.x = (v[4] - mu) * rs * gB.x + bB.x;
  oB.y = (v[5] - mu) * rs * gB.y + bB.y;
  oB.z = (v[6] - mu) * rs * gB.z + bB.z;
  oB.w = (v[7] - mu) * rs * gB.w + bB.w;
  *reinterpret_cast<float4*>(out + base) = oA;
  *reinterpret_cast<float4*>(out + base + 4) = oB;
}

// ===========================================================================
// Tier-2 fallback (round-5 validated): fused-quant bf16 GEMM + resid -> ybf.
// ===========================================================================
#define BMv 128
#define BNv 128
#define BKv 32

__global__ __launch_bounds__(256) void gemm_fa_kernel(
    const float* __restrict__ hidden, const unsigned short* __restrict__ Wq,
    const float* __restrict__ bias, const float* __restrict__ resid,
    const float* __restrict__ scales, unsigned short* __restrict__ ybf, int M) {
  __shared__ __attribute__((aligned(16))) unsigned short SM[17408];
  unsigned short* As = SM;
  unsigned short* Bs = SM + 8192;
  const int nwg = (M / BMv) * 8;
  const int orig = blockIdx.x;
  const int cpx = nwg >> 3;
  const int wg = ((nwg & 7) == 0) ? ((orig & 7) * cpx + (orig >> 3)) : orig;
  const int bn = wg & 7, bm = wg >> 3;
  const int m0 = bm * BMv, n0 = bn * BNv;
  const int t = threadIdx.x;
  const int lane = t & 63, wid = t >> 6;
  const int wr = wid >> 1, wc = wid & 1;
  const int lrow = lane & 15, lgrp = lane >> 4;
  const float amax_h = fmaxf(scales[0], 1e-8f);
  const float amax_w = fmaxf(scales[1], 1e-8f);
  const float sh = QMAX / amax_h;
  const float inv_s = (amax_h * amax_w) / (QMAX * QMAX);
  const int a_row = t >> 1, a_half = t & 1;
  const float* Ag = hidden + (size_t)(m0 + a_row) * H_DIM + a_half * 16;
  const int a_swz = (a_row >> 1) & 3;
  const int aw0 = a_row * 32 + (((a_half * 2 + 0) ^ a_swz) * 8);
  const int aw1 = a_row * 32 + (((a_half * 2 + 1) ^ a_swz) * 8);
  const int bc0 = t, bc1 = t + 256;
  const int br0 = bc0 >> 2, br1 = bc1 >> 2;
  const unsigned bg0 = (unsigned)br0 * H_DIM + (unsigned)((((bc0 & 3) ^ ((br0 >> 1) & 3))) * 8);
  const unsigned bg1 = (unsigned)br1 * H_DIM + (unsigned)((((bc1 & 3) ^ ((br1 >> 1) & 3))) * 8);
  const unsigned short* Bg = Wq + (size_t)n0 * H_DIM;
  int offA[4], offB[4];
#pragma unroll
  for (int i = 0; i < 4; ++i) {
    const int r = wr * 64 + i * 16 + lrow;
    offA[i] = r * 32 + ((lgrp ^ ((r >> 1) & 3)) * 8);
  }
#pragma unroll
  for (int j = 0; j < 4; ++j) {
    const int r = wc * 64 + j * 16 + lrow;
    offB[j] = r * 32 + ((lgrp ^ ((r >> 1) & 3)) * 8);
  }
  f32x4 acc[4][4];
#pragma unroll
  for (int i = 0; i < 4; i++)
#pragma unroll
    for (int j = 0; j < 4; j++)
#pragma unroll
      for (int r = 0; r < 4; r++) acc[i][j][r] = 0.f;
#define QUANT_PACK(dst0, dst1, v0, v1, v2, v3)                                 \
  {                                                                            \
    u16x8 p0, p1;                                                              \
    p0[0] = quant_bf16((v0).x, sh); p0[1] = quant_bf16((v0).y, sh);            \
    p0[2] = quant_bf16((v0).z, sh); p0[3] = quant_bf16((v0).w, sh);            \
    p0[4] = quant_bf16((v1).x, sh); p0[5] = quant_bf16((v1).y, sh);            \
    p0[6] = quant_bf16((v1).z, sh); p0[7] = quant_bf16((v1).w, sh);            \
    p1[0] = quant_bf16((v2).x, sh); p1[1] = quant_bf16((v2).y, sh);            \
    p1[2] = quant_bf16((v2).z, sh); p1[3] = quant_bf16((v2).w, sh);            \
    p1[4] = quant_bf16((v3).x, sh); p1[5] = quant_bf16((v3).y, sh);            \
    p1[6] = quant_bf16((v3).z, sh); p1[7] = quant_bf16((v3).w, sh);            \
    *reinterpret_cast<u16x8*>(dst0) = p0;                                      \
    *reinterpret_cast<u16x8*>(dst1) = p1;                                      \
  }
  {
    const float4 v0 = *reinterpret_cast<const float4*>(Ag + 0);
    const float4 v1 = *reinterpret_cast<const float4*>(Ag + 4);
    const float4 v2 = *reinterpret_cast<const float4*>(Ag + 8);
    const float4 v3 = *reinterpret_cast<const float4*>(Ag + 12);
    __builtin_amdgcn_global_load_lds((gmem_void*)(Bg + bg0), (lds_void*)(Bs + bc0 * 8), 16, 0, 0);
    __builtin_amdgcn_global_load_lds((gmem_void*)(Bg + bg1), (lds_void*)(Bs + bc1 * 8), 16, 0, 0);
    QUANT_PACK(As + aw0, As + aw1, v0, v1, v2, v3)
    __syncthreads();
  }
  for (int it = 0; it < H_DIM / BKv; ++it) {
    const int cur = it & 1, nxt = cur ^ 1;
    const bool more = (it + 1) < (H_DIM / BKv);
    float4 v0, v1, v2, v3;
    if (more) {
      const float* Agn = Ag + (it + 1) * BKv;
      v0 = *reinterpret_cast<const float4*>(Agn + 0);
      v1 = *reinterpret_cast<const float4*>(Agn + 4);
      v2 = *reinterpret_cast<const float4*>(Agn + 8);
      v3 = *reinterpret_cast<const float4*>(Agn + 12);
      const unsigned kq = (unsigned)((it + 1) * BKv);
      __builtin_amdgcn_global_load_lds((gmem_void*)(Bg + bg0 + kq),
                                       (lds_void*)(Bs + nxt * 4096 + bc0 * 8), 16, 0, 0);
      __builtin_amdgcn_global_load_lds((gmem_void*)(Bg + bg1 + kq),
                                       (lds_void*)(Bs + nxt * 4096 + bc1 * 8), 16, 0, 0);
    }
    bf16x8 af[4], bfr[4];
#pragma unroll
    for (int i = 0; i < 4; ++i)
      af[i] = *reinterpret_cast<const bf16x8*>(As + cur * 4096 + offA[i]);
#pragma unroll
    for (int j = 0; j < 4; ++j)
      bfr[j] = *reinterpret_cast<const bf16x8*>(Bs + cur * 4096 + offB[j]);
    __builtin_amdgcn_s_setprio(1);
#pragma unroll
    for (int i = 0; i < 4; ++i)
#pragma unroll
      for (int j = 0; j < 4; ++j)
        acc[i][j] = __builtin_amdgcn_mfma_f32_16x16x32_bf16(af[i], bfr[j], acc[i][j], 0, 0, 0);
    __builtin_amdgcn_s_setprio(0);
    if (more) {
      QUANT_PACK(As + nxt * 4096 + aw0, As + nxt * 4096 + aw1, v0, v1, v2, v3)
    }
    __syncthreads();
  }
#pragma unroll
  for (int j = 0; j < 4; ++j) {
    const int cl = wc * 64 + j * 16 + lrow;
    const float bv = bias[n0 + cl];
#pragma unroll
    for (int i = 0; i < 4; ++i) {
      const int rl0 = wr * 64 + i * 16 + lgrp * 4;
#pragma unroll
      for (int r = 0; r < 4; ++r) {
        const float y = acc[i][j][r] * inv_s + bv +
                        resid[(size_t)(m0 + rl0 + r) * H_DIM + n0 + cl];
        SM[(rl0 + r) * 136 + cl] = f2bf_rne(y);
      }
    }
  }
  __syncthreads();
  {
    const int e_row = t >> 1, e_half = t & 1;
    unsigned short* dst = ybf + (size_t)(m0 + e_row) * H_DIM + n0 + e_half * 64;
    const unsigned short* src = SM + e_row * 136 + e_half * 64;
#pragma unroll
    for (int c = 0; c < 8; ++c)
      *reinterpret_cast<u16x8*>(dst + c * 8) =
          *reinterpret_cast<const u16x8*>(src + c * 8);
  }
#undef QUANT_PACK
}

__global__ __launch_bounds__(256) void ln_bf16_kernel(
    const unsigned short* __restrict__ ybf, const float* __restrict__ gamma,
    const float* __restrict__ beta, float* __restrict__ out) {
  const size_t base = (size_t)blockIdx.x * H_DIM + threadIdx.x * 4;
  const ushort4 u = *reinterpret_cast<const ushort4*>(ybf + base);
  float4 v;
  v.x = bf2f(u.x); v.y = bf2f(u.y); v.z = bf2f(u.z); v.w = bf2f(u.w);
  float s = v.x + v.y + v.z + v.w;
  float ss = v.x * v.x + v.y * v.y + v.z * v.z + v.w * v.w;
#pragma unroll
  for (int off = 32; off > 0; off >>= 1) {
    s += __shfl_down(s, off);
    ss += __shfl_down(ss, off);
  }
  __shared__ float red[8];
  const int lane = threadIdx.x & 63, w = threadIdx.x >> 6;
  if (lane == 0) { red[w] = s; red[4 + w] = ss; }
  __syncthreads();
  const float stot = red[0] + red[1] + red[2] + red[3];
  const float sstot = red[4] + red[5] + red[6] + red[7];
  const float mu = stot * (1.0f / H_DIM);
  const float var = fmaxf(sstot * (1.0f / H_DIM) - mu * mu, 0.f);
  const float rs = rsqrtf(var + 1e-12f);
  const float4 g = *reinterpret_cast<const float4*>(gamma + threadIdx.x * 4);
  const float4 b = *reinterpret_cast<const float4*>(beta + threadIdx.x * 4);
  float4 o;
  o.x = (v.x - mu) * rs * g.x + b.x;
  o.y = (v.y - mu) * rs * g.y + b.y;
  o.z = (v.z - mu) * rs * g.z + b.z;
  o.w = (v.w - mu) * rs * g.w + b.w;
  *reinterpret_cast<float4*>(out + base) = o;
}

// ===========================================================================
// Tier-3 fallback (round-1 validated).
// ===========================================================================
#define BM 128
#define BN 128
#define BK 32

__global__ __launch_bounds__(256, 2) void gemm_fused_kernel(
    const float* __restrict__ A, const unsigned short* __restrict__ Wq,
    const float* __restrict__ bias, const float* __restrict__ resid,
    const float* __restrict__ scales, float* __restrict__ out, int M) {
  __shared__ unsigned short Asf[BM][40];
  __shared__ unsigned short Bsf[BN][40];
  const int nbm = M / BM;
  const int bm = blockIdx.x % nbm, bn = blockIdx.x / nbm;
  const int m0 = bm * BM, n0 = bn * BN;
  const int t = threadIdx.x;
  const int lane = t & 63, wid = t >> 6;
  const int wr = wid >> 1, wc = wid & 1;
  const int lrow = lane & 15, lgrp = lane >> 4;
  const float amax_h = fmaxf(scales[0], 1e-8f);
  const float amax_w = fmaxf(scales[1], 1e-8f);
  const float sh = QMAX / amax_h;
  const float inv_s = (amax_h * amax_w) / (QMAX * QMAX);
  f32x4 acc[4][4];
#pragma unroll
  for (int i = 0; i < 4; i++)
#pragma unroll
    for (int j = 0; j < 4; j++)
#pragma unroll
      for (int r = 0; r < 4; r++) acc[i][j][r] = 0.f;
  for (int k0 = 0; k0 < H_DIM; k0 += BK) {
#pragma unroll
    for (int j = 0; j < 4; ++j) {
      const int f = j * 256 + t;
      const int r = f >> 3, c4 = f & 7;
      const float4 v = *reinterpret_cast<const float4*>(A + (size_t)(m0 + r) * H_DIM + k0 + c4 * 4);
      ushort4 q;
      q.x = quant_bf16(v.x, sh); q.y = quant_bf16(v.y, sh);
      q.z = quant_bf16(v.z, sh); q.w = quant_bf16(v.w, sh);
      *reinterpret_cast<ushort4*>(&Asf[r][c4 * 4]) = q;
    }
#pragma unroll
    for (int j = 0; j < 2; ++j) {
      const int f = j * 256 + t;
      const int r = f >> 2, cb = f & 3;
      const uint4 v = *reinterpret_cast<const uint4*>(Wq + (size_t)(n0 + r) * H_DIM + k0 + cb * 8);
      *reinterpret_cast<uint4*>(&Bsf[r][cb * 8]) = v;
    }
    __syncthreads();
    bf16x8 af[4], bfr[4];
#pragma unroll
    for (int i = 0; i < 4; i++)
      af[i] = *reinterpret_cast<const bf16x8*>(&Asf[wr * 64 + i * 16 + lrow][lgrp * 8]);
#pragma unroll
    for (int j = 0; j < 4; j++)
      bfr[j] = *reinterpret_cast<const bf16x8*>(&Bsf[wc * 64 + j * 16 + lrow][lgrp * 8]);
#pragma unroll
    for (int i = 0; i < 4; i++)
#pragma unroll
      for (int j = 0; j < 4; j++)
        acc[i][j] = __builtin_amdgcn_mfma_f32_16x16x32_bf16(af[i], bfr[j], acc[i][j], 0, 0, 0);
    __syncthreads();
  }
#pragma unroll
  for (int j = 0; j < 4; j++) {
    const int col = n0 + wc * 64 + j * 16 + lrow;
    const float bv = bias[col];
#pragma unroll
    for (int i = 0; i < 4; i++) {
      const int row0 = m0 + wr * 64 + i * 16 + lgrp * 4;
#pragma unroll
      for (int r = 0; r < 4; r++) {
        const size_t off = (size_t)(row0 + r) * H_DIM + col;
        out[off] = acc[i][j][r] * inv_s + bv + resid[off];
      }
    }
  }
}

__global__ __launch_bounds__(256) void ln_kernel(
    float* __restrict__ y, const float* __restrict__ gamma,
    const float* __restrict__ beta) {
  const size_t base = (size_t)blockIdx.x * H_DIM + threadIdx.x * 4;
  const float4 v = *reinterpret_cast<const float4*>(y + base);
  float s = v.x + v.y + v.z + v.w;
  float ss = v.x * v.x + v.y * v.y + v.z * v.z + v.w * v.w;
#pragma unroll
  for (int off = 32; off > 0; off >>= 1) {
    s += __shfl_down(s, off);
    ss += __shfl_down(ss, off);
  }
  __shared__ float red[8];
  const int lane = threadIdx.x & 63, w = threadIdx.x >> 6;
  if (lane == 0) { red[w] = s; red[4 + w] = ss; }
  __syncthreads();
  const float stot = red[0] + red[1] + red[2] + red[3];
  const float sstot = red[4] + red[5] + red[6] + red[7];
  const float mu = stot * (1.0f / H_DIM);
  const float var = fmaxf(sstot * (1.0f / H_DIM) - mu * mu, 0.f);
  const float rs = rsqrtf(var + 1e-12f);
  const float4 g = *reinterpret_cast<const float4*>(gamma + threadIdx.x * 4);
  const float4 b = *reinterpret_cast<const float4*>(beta + threadIdx.x * 4);
  float4 o;
  o.x = (v.x - mu) * rs * g.x + b.x;
  o.y = (v.y - mu) * rs * g.y + b.y;
  o.z = (v.z - mu) * rs * g.z + b.z;
  o.w = (v.w - mu) * rs * g.w + b.w;
  *reinterpret_cast<float4*>(y + base) = o;
}

extern "C" void kernel_launch(void* const* d_in, const int* in_sizes, int n_in,
                              void* d_out, int out_size, void* d_ws, size_t ws_size,
                              hipStream_t stream) {
  const float* hidden = (const float*)d_in[0];
  const float* resid  = (const float*)d_in[1];
  const float* weight = (const float*)d_in[2];
  const float* bias   = (const float*)d_in[3];
  const float* gamma  = (const float*)d_in[4];
  const float* beta   = (const float*)d_in[5];
  float* out = (float*)d_out;

  const long nh = (long)in_sizes[0];   // B*S*H
  const int M = (int)(nh / H_DIM);     // 32768
  const long nw = (long)H_DIM * H_DIM;

  float* scales = (float*)d_ws;                         // [0]=amax_h,[1]=amax_w
  char* base = (char*)d_ws + 256;
  // main (i8) path layout:
  signed char* Wq8 = (signed char*)base;                // 1 MB
  signed char* Aq8 = (signed char*)(base + nw);         // nh bytes
  unsigned short* gbf = (unsigned short*)(base + nw + nh);  // nh*2 bytes
  const size_t need1 = 256 + (size_t)nw + (size_t)nh * 3;
  // fallback (bf16) layout:
  unsigned short* Wq = (unsigned short*)base;           // 2 MB
  unsigned short* ybf = (unsigned short*)(base + nw * 2);
  const size_t need2 = 256 + (size_t)nw * 2 + (size_t)nh * 2;

  hipMemsetAsync(d_ws, 0, 8, stream);
  absmax_clip_kernel<<<2048, 256, 0, stream>>>(hidden, nh, scales + 0);
  absmax_clip_kernel<<<256, 256, 0, stream>>>(weight, nw, scales + 1);

  if (ws_size >= need1 && (M % BMs) == 0 && (M % 2) == 0) {
    quant8_kernel<<<512, 256, 0, stream>>>(weight, Wq8, scales + 1, nw);
    quant8_kernel<<<2048, 256, 0, stream>>>(hidden, Aq8, scales + 0, nh);
    gemm_s8_kernel<<<(M / BMs) * (H_DIM / BNs), 256, 0, stream>>>(
        Aq8, Wq8, bias, scales, gbf, M);
    ln_resid_kernel<<<M / 2, 256, 0, stream>>>(gbf, resid, gamma, beta, out);
  } else if (ws_size >= need2 && (M % BMv) == 0) {
    quant_kernel<<<1024, 256, 0, stream>>>(weight, Wq, scales + 1, nw);
    gemm_fa_kernel<<<(M / BMv) * (H_DIM / BNv), 256, 0, stream>>>(
        hidden, Wq, bias, resid, scales, ybf, M);
    ln_bf16_kernel<<<M, 256, 0, stream>>>(ybf, gamma, beta, out);
  } else {
    unsigned short* Wqf = (unsigned short*)base;
    quant_kernel<<<1024, 256, 0, stream>>>(weight, Wqf, scales + 1, nw);
    gemm_fused_kernel<<<(M / BM) * (H_DIM / BN), 256, 0, stream>>>(
        hidden, Wqf, bias, resid, scales, out, M);
    ln_kernel<<<M, 256, 0, stream>>>(out, gamma, beta);
  }
}